// Round 15
// baseline (1436.205 us; speedup 1.0000x reference)
//
#include <hip/hip_runtime.h>

constexpr int G    = 8;
constexpr int NN   = 50000;
constexpr int EE   = 800000;
constexpr int F    = 128;
constexpr int NBK  = (NN + 255) / 256;   // 196 buckets of 256 nodes
constexpr int CAP2 = 4608;               // bucket cap: mean 4096 + 8 sigma
constexpr int CHA  = 8192;               // edges per binA block
constexpr int NBA  = (EE + CHA - 1) / CHA;   // 98 binA blocks per graph

typedef float  float4_t __attribute__((ext_vector_type(4)));
typedef float  f32x4    __attribute__((ext_vector_type(4)));
typedef __bf16 bf16x8   __attribute__((ext_vector_type(8)));
typedef unsigned short u16x4 __attribute__((ext_vector_type(4)));
typedef unsigned short u16x8 __attribute__((ext_vector_type(8)));
typedef int            i32x4 __attribute__((ext_vector_type(4)));

__device__ inline float bf2f(unsigned short u) {
  union { unsigned int i; float f; } v; v.i = (unsigned int)u << 16; return v.f;
}
__device__ inline unsigned short f2bf(float f) {
  union { __bf16 b; unsigned short u; } v; v.b = (__bf16)f; return v.u;   // RNE
}
__device__ inline void addrow(f32x4& a, f32x4& b, u16x8 v) {
  a += (f32x4){bf2f(v[0]), bf2f(v[1]), bf2f(v[2]), bf2f(v[3])};
  b += (f32x4){bf2f(v[4]), bf2f(v[5]), bf2f(v[6]), bf2f(v[7])};
}

// ---------------- build pass A: LDS-histogram bucket binning (r13, proven) ----------------

__global__ __launch_bounds__(256) void binA_kernel(const int* __restrict__ edges,
                                                   int* __restrict__ bcur,
                                                   unsigned int* __restrict__ tmp,
                                                   int gbase, int Cg) {
  __shared__ int hist[NBK];
  __shared__ int hbase[NBK];
  int bid = blockIdx.x;
  int gw = bid % Cg, cb = bid / Cg;
  size_t ebase = (size_t)(gbase + gw) * 2 * EE;
  const int* srcp = edges + ebase;
  const int* dstp = edges + ebase + EE;
  int t = threadIdx.x;
  for (int i = t; i < NBK; i += 256) hist[i] = 0;
  __syncthreads();
  int e0 = cb * CHA;
  #pragma unroll
  for (int p = 0; p < CHA / 1024; ++p) {     // sweep 1: count
    int e = e0 + (p * 256 + t) * 4;
    if (e < EE) {
      i32x4 d4 = __builtin_nontemporal_load((const i32x4*)(dstp + e));
      atomicAdd(&hist[d4.x >> 8], 1);
      atomicAdd(&hist[d4.y >> 8], 1);
      atomicAdd(&hist[d4.z >> 8], 1);
      atomicAdd(&hist[d4.w >> 8], 1);
    }
  }
  __syncthreads();
  for (int i = t; i < NBK; i += 256) {       // reserve bucket space
    int c = hist[i];
    hbase[i] = c ? atomicAdd(&bcur[gw * NBK + i], c) : 0;
    hist[i] = 0;                             // becomes block-local cursor
  }
  __syncthreads();
  unsigned int* tg = tmp + (size_t)gw * NBK * CAP2;
  #pragma unroll
  for (int p = 0; p < CHA / 1024; ++p) {     // sweep 2: scatter packed edges
    int e = e0 + (p * 256 + t) * 4;
    if (e < EE) {
      i32x4 s4 = __builtin_nontemporal_load((const i32x4*)(srcp + e));
      i32x4 d4 = __builtin_nontemporal_load((const i32x4*)(dstp + e));
      int dd[4] = {d4.x, d4.y, d4.z, d4.w};
      int ss[4] = {s4.x, s4.y, s4.z, s4.w};
      #pragma unroll
      for (int j = 0; j < 4; ++j) {
        int b = dd[j] >> 8;
        int pos = hbase[b] + atomicAdd(&hist[b], 1);
        if (pos < CAP2)
          tg[(size_t)b * CAP2 + pos] = ((unsigned)(dd[j] & 255) << 16) | (unsigned)ss[j];
      }
    }
  }
}

// ---------------- tiny exclusive scan of the 196 bucket counts ----------------

__global__ __launch_bounds__(256) void bscan_kernel(const int* __restrict__ bcur,
                                                    int* __restrict__ bbase) {
  __shared__ int wsum[4];
  int gw = blockIdx.x;
  int t = threadIdx.x;
  int lane = t & 63, wid = t >> 6;
  int v = (t < NBK) ? bcur[gw * NBK + t] : 0;
  int incl = v;
  #pragma unroll
  for (int off = 1; off < 64; off <<= 1) {
    int x = __shfl_up(incl, off);
    if (lane >= off) incl += x;
  }
  if (lane == 63) wsum[wid] = incl;
  __syncthreads();
  if (t == 0) {
    int s = 0;
    for (int w = 0; w < 4; ++w) { int x = wsum[w]; wsum[w] = s; s += x; }
  }
  __syncthreads();
  if (t < NBK) bbase[gw * NBK + t] = wsum[wid] + incl - v;
}

// ---------------- build pass B: per-bucket counting sort -> CSR + row_off + dinv ----

__global__ __launch_bounds__(256) void binB_kernel(const unsigned int* __restrict__ tmp,
                                                   const int* __restrict__ bcur,
                                                   const int* __restrict__ bbase,
                                                   unsigned short* __restrict__ csr,
                                                   int* __restrict__ row_off,
                                                   float* __restrict__ dinv, int Cg) {
  __shared__ int cnt256[256];
  __shared__ int cur256[256];
  __shared__ int wsum[4];
  int bid = blockIdx.x;
  int gw = bid % Cg, b = bid / Cg;
  int t = threadIdx.x;
  int cnt = bcur[gw * NBK + b]; if (cnt > CAP2) cnt = CAP2;
  int bb = bbase[gw * NBK + b];
  const unsigned int* tg = tmp + ((size_t)gw * NBK + b) * CAP2;
  int n0 = b << 8;
  int nNode = NN - n0; if (nNode > 256) nNode = 256;
  cnt256[t] = 0;
  __syncthreads();
  for (int i = t; i < cnt; i += 256)
    atomicAdd(&cnt256[tg[i] >> 16], 1);
  __syncthreads();
  int v = cnt256[t];
  int lane = t & 63, wid = t >> 6;
  int incl = v;
  #pragma unroll
  for (int off = 1; off < 64; off <<= 1) {
    int x = __shfl_up(incl, off);
    if (lane >= off) incl += x;
  }
  if (lane == 63) wsum[wid] = incl;
  __syncthreads();
  if (t == 0) {
    int s = 0;
    for (int w = 0; w < 4; ++w) { int x = wsum[w]; wsum[w] = s; s += x; }
  }
  __syncthreads();
  int excl = wsum[wid] + incl - v;
  cur256[t] = excl;
  int* ro = row_off + gw * (NN + 1);
  if (t < nNode) {
    ro[n0 + t] = bb + excl;
    (dinv + (size_t)gw * NN)[n0 + t] = rsqrtf((float)v + 1.0f);
  }
  if (b == NBK - 1 && t == nNode) ro[NN] = bb + cnt;   // == EE
  __syncthreads();
  unsigned short* cg = csr + (size_t)gw * EE;
  for (int i = t; i < cnt; i += 256) {
    unsigned int u = tg[i];
    int slot = atomicAdd(&cur256[u >> 16], 1);
    cg[bb + slot] = (unsigned short)(u & 0xffff);
  }
}

// ---------------- W^T hi/lo precompute ----------------

__global__ __launch_bounds__(256) void wtprep_kernel(const float* __restrict__ W0,
                                                     const float* __restrict__ W1,
                                                     const float* __restrict__ W2,
                                                     __bf16* __restrict__ wt) {
  const float* Wl[3] = {W0, W1, W2};
  int l = blockIdx.x;
  const float* W = Wl[l];
  __bf16* hi = wt + (size_t)l * 2 * F * F;
  __bf16* lo = hi + F * F;
  for (int idx = threadIdx.x; idx < F * F; idx += 256) {
    int k = idx >> 7, c = idx & 127;
    float f = W[idx];
    __bf16 h = (__bf16)f;
    hi[c * F + k] = h;                  // transposed: [col][k]
    lo[c * F + k] = (__bf16)(f - (float)h);
  }
}

// ---------------- W-stationary persistent-wave GEMM (r9 proven) ----------------

template<int MODE>
__global__ __launch_bounds__(256) void gemm_kernel(const void* __restrict__ actp,
                                                   const __bf16* __restrict__ wt,
                                                   const float* __restrict__ dinv,
                                                   unsigned short* __restrict__ h1,
                                                   int gbase, int Cg) {
  int w = threadIdx.x >> 6, l = threadIdx.x & 63;
  int wave = blockIdx.x * 4 + w;
  int cg  = wave & 3;                 // col-group: cols [cg*32, cg*32+32)
  int i16 = l & 15, kq = l >> 4;

  bf16x8 Bhi[2][4], Blo[2][4];        // stationary W^T frags: 64 VGPRs
  #pragma unroll
  for (int t2 = 0; t2 < 2; ++t2) {
    int col = cg * 32 + t2 * 16 + i16;
    #pragma unroll
    for (int ks = 0; ks < 4; ++ks) {
      Bhi[t2][ks] = *(const bf16x8*)(wt +         (size_t)col * F + ks * 32 + kq * 8);
      Blo[t2][ks] = *(const bf16x8*)(wt + F * F + (size_t)col * F + ks * 32 + kq * 8);
    }
  }

  int ntask = Cg * 3125 * 4;
  int stride = gridDim.x * 4;
  for (int task = wave; task < ntask; task += stride) {
    int chunk = task >> 2;
    int gw = chunk / 3125, ch = chunk - gw * 3125;
    int row = ch * 16 + i16;
    size_t rbase = (size_t)row * F + kq * 8;

    f32x4 acc0 = {0.f, 0.f, 0.f, 0.f}, acc1 = acc0;
    if (MODE == 0) {
      const float* ag = (const float*)actp + (size_t)(gbase + gw) * NN * F;
      #pragma unroll
      for (int ks = 0; ks < 4; ++ks) {
        float4_t v0 = *(const float4_t*)(ag + rbase + ks * 32);
        float4_t v1 = *(const float4_t*)(ag + rbase + ks * 32 + 4);
        bf16x8 ahi, alo;
        #pragma unroll
        for (int j = 0; j < 4; ++j) {
          __bf16 h0 = (__bf16)v0[j], h1v = (__bf16)v1[j];
          ahi[j] = h0;     ahi[j + 4] = h1v;
          alo[j] = (__bf16)(v0[j] - (float)h0);
          alo[j + 4] = (__bf16)(v1[j] - (float)h1v);
        }
        acc0 = __builtin_amdgcn_mfma_f32_16x16x32_bf16(Bhi[0][ks], ahi, acc0, 0, 0, 0);
        acc0 = __builtin_amdgcn_mfma_f32_16x16x32_bf16(Blo[0][ks], ahi, acc0, 0, 0, 0);
        acc0 = __builtin_amdgcn_mfma_f32_16x16x32_bf16(Bhi[0][ks], alo, acc0, 0, 0, 0);
        acc1 = __builtin_amdgcn_mfma_f32_16x16x32_bf16(Bhi[1][ks], ahi, acc1, 0, 0, 0);
        acc1 = __builtin_amdgcn_mfma_f32_16x16x32_bf16(Blo[1][ks], ahi, acc1, 0, 0, 0);
        acc1 = __builtin_amdgcn_mfma_f32_16x16x32_bf16(Bhi[1][ks], alo, acc1, 0, 0, 0);
      }
    } else {
      const unsigned short* ag = (const unsigned short*)actp + (size_t)gw * NN * F;
      #pragma unroll
      for (int ks = 0; ks < 4; ++ks) {
        bf16x8 a = *(const bf16x8*)((const __bf16*)ag + rbase + ks * 32);
        acc0 = __builtin_amdgcn_mfma_f32_16x16x32_bf16(Bhi[0][ks], a, acc0, 0, 0, 0);
        acc0 = __builtin_amdgcn_mfma_f32_16x16x32_bf16(Blo[0][ks], a, acc0, 0, 0, 0);
        acc1 = __builtin_amdgcn_mfma_f32_16x16x32_bf16(Bhi[1][ks], a, acc1, 0, 0, 0);
        acc1 = __builtin_amdgcn_mfma_f32_16x16x32_bf16(Blo[1][ks], a, acc1, 0, 0, 0);
      }
    }
    float di = (dinv + (size_t)gw * NN)[row];
    unsigned short* hr = h1 + (size_t)gw * NN * F + (size_t)row * F + cg * 32 + kq * 4;
    u16x4 o0, o1;
    #pragma unroll
    for (int q = 0; q < 4; ++q) { o0[q] = f2bf(acc0[q] * di); o1[q] = f2bf(acc1[q] * di); }
    *(u16x4*)hr = o0;
    *(u16x4*)(hr + 16) = o1;
  }
}

// ---------------- quartered aggregation: 4 lanes/node, one 64B line per gather ----
// Per dispatch q, only cols [q*32, q*32+32) are gathered: working set 3.2MB/graph
// fits one XCD L2 (gw = bid%Cg pinning). CSR loads + output stores nontemporal so
// the hot quarter stays resident. Column math is identical -> bit-exact vs full agg.

template<int FIN>
__global__ __launch_bounds__(256) void agg_kernel(const unsigned short* __restrict__ h1,
                                                  const unsigned short* __restrict__ csr,
                                                  const int* __restrict__ row_off,
                                                  const float* __restrict__ dinv,
                                                  const float* __restrict__ bias,
                                                  void* __restrict__ outp, int gbase, int Cg,
                                                  int q) {
  int bid = blockIdx.x;
  int gw = bid % Cg, xb = bid / Cg;
  const unsigned short* hg = h1 + (size_t)gw * NN * F + q * 32;   // quarter base
  const unsigned short* cs = csr + (size_t)gw * EE;
  const int*   ro = row_off + gw * (NN + 1);
  const float* dv = dinv + (size_t)gw * NN;

  int grp = threadIdx.x >> 2, lane = threadIdx.x & 3;
  int node = xb * 64 + grp;
  if (node >= NN) return;
  int e0 = ro[node], e1 = ro[node + 1];
  float di = dv[node];
  f32x4 a0 = {0.f, 0.f, 0.f, 0.f}, b0 = a0, a1 = a0, b1 = a0;
  addrow(a0, b0, *(const u16x8*)(hg + (size_t)node * F + lane * 8));   // self (scaled)
  int e = e0;
  for (; e + 3 < e1; e += 4) {
    int s0 = (int)__builtin_nontemporal_load(cs + e);
    int s1 = (int)__builtin_nontemporal_load(cs + e + 1);
    int s2 = (int)__builtin_nontemporal_load(cs + e + 2);
    int s3 = (int)__builtin_nontemporal_load(cs + e + 3);
    u16x8 v0 = *(const u16x8*)(hg + (size_t)s0 * F + lane * 8);
    u16x8 v1 = *(const u16x8*)(hg + (size_t)s1 * F + lane * 8);
    u16x8 v2 = *(const u16x8*)(hg + (size_t)s2 * F + lane * 8);
    u16x8 v3 = *(const u16x8*)(hg + (size_t)s3 * F + lane * 8);
    addrow(a0, b0, v0);
    addrow(a1, b1, v1);
    addrow(a0, b0, v2);
    addrow(a1, b1, v3);
  }
  for (; e < e1; ++e) {
    int s = (int)__builtin_nontemporal_load(cs + e);
    addrow(a0, b0, *(const u16x8*)(hg + (size_t)s * F + lane * 8));
  }
  f32x4 ra = a0 + a1, rb = b0 + b1;
  const float* bq = bias + q * 32;
  float4_t bb0 = *(const float4_t*)(bq + lane * 8);
  float4_t bb1 = *(const float4_t*)(bq + lane * 8 + 4);
  #pragma unroll
  for (int j = 0; j < 4; ++j) {
    ra[j] = fmaxf(fmaf(ra[j], di, bb0[j]), 0.f);
    rb[j] = fmaxf(fmaf(rb[j], di, bb1[j]), 0.f);
  }
  if (FIN) {
    float* og = (float*)outp + (size_t)(gbase + gw) * NN * F + (size_t)node * F + q * 32 + lane * 8;
    __builtin_nontemporal_store(ra, (f32x4*)og);
    __builtin_nontemporal_store(rb, (f32x4*)(og + 4));
  } else {
    u16x8 o;
    #pragma unroll
    for (int j = 0; j < 4; ++j) { o[j] = f2bf(ra[j]); o[j + 4] = f2bf(rb[j]); }
    unsigned short* og = (unsigned short*)outp + (size_t)gw * NN * F + (size_t)node * F + q * 32 + lane * 8;
    __builtin_nontemporal_store(o, (u16x8*)og);
  }
}

// ---------------- host launch ----------------

extern "C" void kernel_launch(void* const* d_in, const int* in_sizes, int n_in,
                              void* d_out, int out_size, void* d_ws, size_t ws_size,
                              hipStream_t stream) {
  const float* x     = (const float*)d_in[0];
  const int*   edges = (const int*)d_in[1];
  const float* Ws[3] = {(const float*)d_in[2], (const float*)d_in[4], (const float*)d_in[6]};
  const float* bs[3] = {(const float*)d_in[3], (const float*)d_in[5], (const float*)d_in[7]};
  float* out = (float*)d_out;

  size_t sz_h1  = (size_t)NN * F * 2;           // 12.8 MB bf16 per graph (x2: ping-pong)
  size_t sz_wt  = (size_t)3 * 2 * F * F * 2;
  size_t sz_csr = (size_t)EE * 2;               // u16 CSR
  size_t sz_bk  = (size_t)NBK * 4;
  size_t sz_dv  = (size_t)NN * 4;
  size_t sz_ro  = (size_t)(NN + 1) * 4;
  // binA tmp (3.6MB) aliases actb: build completes before agg writes actb
  size_t per_g  = 2 * sz_h1 + sz_csr + 2 * sz_bk + sz_dv + sz_ro;  // ~27.8 MB

  int CB = (int)((ws_size > sz_wt ? ws_size - sz_wt : 0) / per_g);
  if (CB < 1) CB = 1;
  if (CB > G) CB = G;

  char* p = (char*)d_ws;
  unsigned short* h1      = (unsigned short*)p;  p += sz_h1 * CB;
  unsigned short* actb    = (unsigned short*)p;  p += sz_h1 * CB;   // also binA tmp
  __bf16*         wt      = (__bf16*)p;          p += sz_wt;
  unsigned short* csr     = (unsigned short*)p;  p += sz_csr * CB;
  int*            bcur    = (int*)p;             p += sz_bk * CB;
  int*            bbase   = (int*)p;             p += sz_bk * CB;
  float*          dinv    = (float*)p;           p += sz_dv * CB;
  int*            row_off = (int*)p;

  wtprep_kernel<<<3, 256, 0, stream>>>(Ws[0], Ws[1], Ws[2], wt);

  int nblk_m = 2048;             // persistent-wave GEMM grid
  int nblk_q = (NN + 63) / 64;   // 782 blocks per graph per quarter

  for (int gb = 0; gb < G; gb += CB) {
    int Cg = G - gb < CB ? G - gb : CB;
    hipMemsetAsync(bcur, 0, sz_bk * Cg, stream);
    binA_kernel <<<NBA * Cg, 256, 0, stream>>>(edges, bcur, (unsigned int*)actb, gb, Cg);
    bscan_kernel<<<Cg, 256, 0, stream>>>(bcur, bbase);
    binB_kernel <<<NBK * Cg, 256, 0, stream>>>((const unsigned int*)actb, bcur, bbase,
                                               csr, row_off, dinv, Cg);

    for (int l = 0; l < 3; ++l) {
      if (l == 0)
        gemm_kernel<0><<<nblk_m, 256, 0, stream>>>(x, wt, dinv, h1, gb, Cg);
      else
        gemm_kernel<1><<<nblk_m, 256, 0, stream>>>(actb, wt + (size_t)l * 2 * F * F,
                                                   dinv, h1, gb, Cg);
      if (l < 2) {
        for (int q = 0; q < 4; ++q)
          agg_kernel<0><<<nblk_q * Cg, 256, 0, stream>>>(h1, csr, row_off, dinv, bs[l],
                                                         actb, gb, Cg, q);
      } else {
        for (int q = 0; q < 4; ++q)
          agg_kernel<1><<<nblk_q * Cg, 256, 0, stream>>>(h1, csr, row_off, dinv, bs[l],
                                                         out, gb, Cg, q);
      }
    }
  }
}

// Round 16
// 964.817 us; speedup vs baseline: 1.4886x; 1.4886x over previous
//
#include <hip/hip_runtime.h>

constexpr int G    = 8;
constexpr int NN   = 50000;
constexpr int EE   = 800000;
constexpr int F    = 128;
constexpr int NBK  = (NN + 255) / 256;   // 196 buckets of 256 nodes
constexpr int CAP2 = 4608;               // bucket cap: mean 4096 + 8 sigma
constexpr int CHA  = 8192;               // edges per binA block
constexpr int NBA  = (EE + CHA - 1) / CHA;   // 98 binA blocks per graph

typedef float  float4_t __attribute__((ext_vector_type(4)));
typedef float  f32x4    __attribute__((ext_vector_type(4)));
typedef __bf16 bf16x8   __attribute__((ext_vector_type(8)));
typedef unsigned short u16x4 __attribute__((ext_vector_type(4)));
typedef unsigned short u16x8 __attribute__((ext_vector_type(8)));
typedef int            i32x4 __attribute__((ext_vector_type(4)));

__device__ inline float bf2f(unsigned short u) {
  union { unsigned int i; float f; } v; v.i = (unsigned int)u << 16; return v.f;
}
__device__ inline unsigned short f2bf(float f) {
  union { __bf16 b; unsigned short u; } v; v.b = (__bf16)f; return v.u;   // RNE
}
__device__ inline void addrow(f32x4& a, f32x4& b, u16x8 v) {
  a += (f32x4){bf2f(v[0]), bf2f(v[1]), bf2f(v[2]), bf2f(v[3])};
  b += (f32x4){bf2f(v[4]), bf2f(v[5]), bf2f(v[6]), bf2f(v[7])};
}

// ---------------- build pass A: LDS-histogram bucket binning (r13, proven) ----------------

__global__ __launch_bounds__(256) void binA_kernel(const int* __restrict__ edges,
                                                   int* __restrict__ bcur,
                                                   unsigned int* __restrict__ tmp,
                                                   int gbase, int Cg) {
  __shared__ int hist[NBK];
  __shared__ int hbase[NBK];
  int bid = blockIdx.x;
  int gw = bid % Cg, cb = bid / Cg;
  size_t ebase = (size_t)(gbase + gw) * 2 * EE;
  const int* srcp = edges + ebase;
  const int* dstp = edges + ebase + EE;
  int t = threadIdx.x;
  for (int i = t; i < NBK; i += 256) hist[i] = 0;
  __syncthreads();
  int e0 = cb * CHA;
  #pragma unroll
  for (int p = 0; p < CHA / 1024; ++p) {     // sweep 1: count
    int e = e0 + (p * 256 + t) * 4;
    if (e < EE) {
      i32x4 d4 = __builtin_nontemporal_load((const i32x4*)(dstp + e));
      atomicAdd(&hist[d4.x >> 8], 1);
      atomicAdd(&hist[d4.y >> 8], 1);
      atomicAdd(&hist[d4.z >> 8], 1);
      atomicAdd(&hist[d4.w >> 8], 1);
    }
  }
  __syncthreads();
  for (int i = t; i < NBK; i += 256) {       // reserve bucket space
    int c = hist[i];
    hbase[i] = c ? atomicAdd(&bcur[gw * NBK + i], c) : 0;
    hist[i] = 0;                             // becomes block-local cursor
  }
  __syncthreads();
  unsigned int* tg = tmp + (size_t)gw * NBK * CAP2;
  #pragma unroll
  for (int p = 0; p < CHA / 1024; ++p) {     // sweep 2: scatter packed edges
    int e = e0 + (p * 256 + t) * 4;
    if (e < EE) {
      i32x4 s4 = __builtin_nontemporal_load((const i32x4*)(srcp + e));
      i32x4 d4 = __builtin_nontemporal_load((const i32x4*)(dstp + e));
      int dd[4] = {d4.x, d4.y, d4.z, d4.w};
      int ss[4] = {s4.x, s4.y, s4.z, s4.w};
      #pragma unroll
      for (int j = 0; j < 4; ++j) {
        int b = dd[j] >> 8;
        int pos = hbase[b] + atomicAdd(&hist[b], 1);
        if (pos < CAP2)
          tg[(size_t)b * CAP2 + pos] = ((unsigned)(dd[j] & 255) << 16) | (unsigned)ss[j];
      }
    }
  }
}

// ---------------- tiny exclusive scan of the 196 bucket counts ----------------

__global__ __launch_bounds__(256) void bscan_kernel(const int* __restrict__ bcur,
                                                    int* __restrict__ bbase) {
  __shared__ int wsum[4];
  int gw = blockIdx.x;
  int t = threadIdx.x;
  int lane = t & 63, wid = t >> 6;
  int v = (t < NBK) ? bcur[gw * NBK + t] : 0;
  int incl = v;
  #pragma unroll
  for (int off = 1; off < 64; off <<= 1) {
    int x = __shfl_up(incl, off);
    if (lane >= off) incl += x;
  }
  if (lane == 63) wsum[wid] = incl;
  __syncthreads();
  if (t == 0) {
    int s = 0;
    for (int w = 0; w < 4; ++w) { int x = wsum[w]; wsum[w] = s; s += x; }
  }
  __syncthreads();
  if (t < NBK) bbase[gw * NBK + t] = wsum[wid] + incl - v;
}

// ---------------- build pass B: per-bucket counting sort -> CSR + row_off + dinv ----

__global__ __launch_bounds__(256) void binB_kernel(const unsigned int* __restrict__ tmp,
                                                   const int* __restrict__ bcur,
                                                   const int* __restrict__ bbase,
                                                   unsigned short* __restrict__ csr,
                                                   int* __restrict__ row_off,
                                                   float* __restrict__ dinv, int Cg) {
  __shared__ int cnt256[256];
  __shared__ int cur256[256];
  __shared__ int wsum[4];
  int bid = blockIdx.x;
  int gw = bid % Cg, b = bid / Cg;
  int t = threadIdx.x;
  int cnt = bcur[gw * NBK + b]; if (cnt > CAP2) cnt = CAP2;
  int bb = bbase[gw * NBK + b];
  const unsigned int* tg = tmp + ((size_t)gw * NBK + b) * CAP2;
  int n0 = b << 8;
  int nNode = NN - n0; if (nNode > 256) nNode = 256;
  cnt256[t] = 0;
  __syncthreads();
  for (int i = t; i < cnt; i += 256)
    atomicAdd(&cnt256[tg[i] >> 16], 1);
  __syncthreads();
  int v = cnt256[t];
  int lane = t & 63, wid = t >> 6;
  int incl = v;
  #pragma unroll
  for (int off = 1; off < 64; off <<= 1) {
    int x = __shfl_up(incl, off);
    if (lane >= off) incl += x;
  }
  if (lane == 63) wsum[wid] = incl;
  __syncthreads();
  if (t == 0) {
    int s = 0;
    for (int w = 0; w < 4; ++w) { int x = wsum[w]; wsum[w] = s; s += x; }
  }
  __syncthreads();
  int excl = wsum[wid] + incl - v;
  cur256[t] = excl;
  int* ro = row_off + gw * (NN + 1);
  if (t < nNode) {
    ro[n0 + t] = bb + excl;
    (dinv + (size_t)gw * NN)[n0 + t] = rsqrtf((float)v + 1.0f);
  }
  if (b == NBK - 1 && t == nNode) ro[NN] = bb + cnt;   // == EE
  __syncthreads();
  unsigned short* cg = csr + (size_t)gw * EE;
  for (int i = t; i < cnt; i += 256) {
    unsigned int u = tg[i];
    int slot = atomicAdd(&cur256[u >> 16], 1);
    cg[bb + slot] = (unsigned short)(u & 0xffff);
  }
}

// ---------------- W^T hi/lo precompute ----------------

__global__ __launch_bounds__(256) void wtprep_kernel(const float* __restrict__ W0,
                                                     const float* __restrict__ W1,
                                                     const float* __restrict__ W2,
                                                     __bf16* __restrict__ wt) {
  const float* Wl[3] = {W0, W1, W2};
  int l = blockIdx.x;
  const float* W = Wl[l];
  __bf16* hi = wt + (size_t)l * 2 * F * F;
  __bf16* lo = hi + F * F;
  for (int idx = threadIdx.x; idx < F * F; idx += 256) {
    int k = idx >> 7, c = idx & 127;
    float f = W[idx];
    __bf16 h = (__bf16)f;
    hi[c * F + k] = h;                  // transposed: [col][k]
    lo[c * F + k] = (__bf16)(f - (float)h);
  }
}

// ---------------- GEMM layer 0: LDS-staged f32 A (coalesced) + register B ----------------
// Block = 64 rows, 4 waves; wave w owns cols [w*32, w*32+32). B-frags load once
// (L2-hot wt), A staged coalesced 16B/lane, frag-read/MFMA/store = r14-verified path.

__global__ __launch_bounds__(256) void gemm0_kernel(const float* __restrict__ act,
                                                    const __bf16* __restrict__ wt,
                                                    const float* __restrict__ dinv,
                                                    unsigned short* __restrict__ h1,
                                                    int gbase, int Cg) {
  __shared__ float As[64][132];
  int bid = blockIdx.x;
  int gw = bid % Cg, xb = bid / Cg;
  const float* ag = act + (size_t)(gbase + gw) * NN * F;
  const float* dv = dinv + (size_t)gw * NN;
  int row0 = xb * 64;
  int t = threadIdx.x;
  int w = t >> 6, l = t & 63;
  int i16 = l & 15, kq = l >> 4;

  bf16x8 Bhi[2][4], Blo[2][4];       // issued first; complete under A-stage
  #pragma unroll
  for (int t2 = 0; t2 < 2; ++t2) {
    int col = w * 32 + t2 * 16 + i16;
    #pragma unroll
    for (int ks = 0; ks < 4; ++ks) {
      Bhi[t2][ks] = *(const bf16x8*)(wt +         (size_t)col * F + ks * 32 + kq * 8);
      Blo[t2][ks] = *(const bf16x8*)(wt + F * F + (size_t)col * F + ks * 32 + kq * 8);
    }
  }

  #pragma unroll
  for (int p = 0; p < 8; ++p) {      // stage 64x128 f32, 16B/lane coalesced
    int idx = p * 256 + t;
    int r = idx >> 5, c = (idx & 31) * 4;
    int grow = row0 + r;
    float4_t v = {0.f, 0.f, 0.f, 0.f};
    if (grow < NN) v = *(const float4_t*)(ag + (size_t)grow * F + c);
    *(float4_t*)(&As[r][c]) = v;
  }
  __syncthreads();

  #pragma unroll
  for (int rt = 0; rt < 4; ++rt) {
    int arow = rt * 16 + i16;
    f32x4 acc0 = {0.f, 0.f, 0.f, 0.f}, acc1 = acc0;
    #pragma unroll
    for (int ks = 0; ks < 4; ++ks) {
      float4_t v0 = *(const float4_t*)(&As[arow][ks * 32 + kq * 8]);
      float4_t v1 = *(const float4_t*)(&As[arow][ks * 32 + kq * 8 + 4]);
      bf16x8 ahi, alo;
      #pragma unroll
      for (int j = 0; j < 4; ++j) {
        __bf16 h0 = (__bf16)v0[j], h1v = (__bf16)v1[j];
        ahi[j] = h0;     ahi[j + 4] = h1v;
        alo[j] = (__bf16)(v0[j] - (float)h0);
        alo[j + 4] = (__bf16)(v1[j] - (float)h1v);
      }
      acc0 = __builtin_amdgcn_mfma_f32_16x16x32_bf16(Bhi[0][ks], ahi, acc0, 0, 0, 0);
      acc0 = __builtin_amdgcn_mfma_f32_16x16x32_bf16(Blo[0][ks], ahi, acc0, 0, 0, 0);
      acc0 = __builtin_amdgcn_mfma_f32_16x16x32_bf16(Bhi[0][ks], alo, acc0, 0, 0, 0);
      acc1 = __builtin_amdgcn_mfma_f32_16x16x32_bf16(Bhi[1][ks], ahi, acc1, 0, 0, 0);
      acc1 = __builtin_amdgcn_mfma_f32_16x16x32_bf16(Blo[1][ks], ahi, acc1, 0, 0, 0);
      acc1 = __builtin_amdgcn_mfma_f32_16x16x32_bf16(Bhi[1][ks], alo, acc1, 0, 0, 0);
    }
    int row = row0 + arow;
    if (row < NN) {
      float di = dv[row];
      unsigned short* hr = h1 + (size_t)gw * NN * F + (size_t)row * F + w * 32 + kq * 4;
      u16x4 o0, o1;
      #pragma unroll
      for (int q = 0; q < 4; ++q) { o0[q] = f2bf(acc0[q] * di); o1[q] = f2bf(acc1[q] * di); }
      *(u16x4*)hr = o0;
      *(u16x4*)(hr + 16) = o1;
    }
  }
}

// ---------------- GEMM layers 1,2: LDS-staged bf16 A + register B ----------------

__global__ __launch_bounds__(256) void gemm1_kernel(const unsigned short* __restrict__ actb,
                                                    const __bf16* __restrict__ wt,
                                                    const float* __restrict__ dinv,
                                                    unsigned short* __restrict__ h1,
                                                    int Cg) {
  __shared__ unsigned short As[64][136];
  int bid = blockIdx.x;
  int gw = bid % Cg, xb = bid / Cg;
  const unsigned short* ag = actb + (size_t)gw * NN * F;
  const float* dv = dinv + (size_t)gw * NN;
  int row0 = xb * 64;
  int t = threadIdx.x;
  int w = t >> 6, l = t & 63;
  int i16 = l & 15, kq = l >> 4;

  bf16x8 Bhi[2][4], Blo[2][4];
  #pragma unroll
  for (int t2 = 0; t2 < 2; ++t2) {
    int col = w * 32 + t2 * 16 + i16;
    #pragma unroll
    for (int ks = 0; ks < 4; ++ks) {
      Bhi[t2][ks] = *(const bf16x8*)(wt +         (size_t)col * F + ks * 32 + kq * 8);
      Blo[t2][ks] = *(const bf16x8*)(wt + F * F + (size_t)col * F + ks * 32 + kq * 8);
    }
  }

  #pragma unroll
  for (int p = 0; p < 4; ++p) {      // stage 64x128 bf16, 16B/lane coalesced
    int idx = p * 256 + t;
    int r = idx >> 4, c = (idx & 15) * 8;
    int grow = row0 + r;
    u16x8 v = (u16x8){0, 0, 0, 0, 0, 0, 0, 0};
    if (grow < NN) v = *(const u16x8*)(ag + (size_t)grow * F + c);
    *(u16x8*)(&As[r][c]) = v;
  }
  __syncthreads();

  #pragma unroll
  for (int rt = 0; rt < 4; ++rt) {
    int arow = rt * 16 + i16;
    f32x4 acc0 = {0.f, 0.f, 0.f, 0.f}, acc1 = acc0;
    #pragma unroll
    for (int ks = 0; ks < 4; ++ks) {
      bf16x8 a = *(const bf16x8*)((const __bf16*)&As[arow][ks * 32 + kq * 8]);
      acc0 = __builtin_amdgcn_mfma_f32_16x16x32_bf16(Bhi[0][ks], a, acc0, 0, 0, 0);
      acc0 = __builtin_amdgcn_mfma_f32_16x16x32_bf16(Blo[0][ks], a, acc0, 0, 0, 0);
      acc1 = __builtin_amdgcn_mfma_f32_16x16x32_bf16(Bhi[1][ks], a, acc1, 0, 0, 0);
      acc1 = __builtin_amdgcn_mfma_f32_16x16x32_bf16(Blo[1][ks], a, acc1, 0, 0, 0);
    }
    int row = row0 + arow;
    if (row < NN) {
      float di = dv[row];
      unsigned short* hr = h1 + (size_t)gw * NN * F + (size_t)row * F + w * 32 + kq * 4;
      u16x4 o0, o1;
      #pragma unroll
      for (int q = 0; q < 4; ++q) { o0[q] = f2bf(acc0[q] * di); o1[q] = f2bf(acc1[q] * di); }
      *(u16x4*)hr = o0;
      *(u16x4*)(hr + 16) = o1;
    }
  }
}

// ---------------- aggregation (r13-proven): 16 lanes/node, u16x8, ILP-4 ----------------

template<int FIN>
__global__ __launch_bounds__(256) void agg_kernel(const unsigned short* __restrict__ h1,
                                                  const unsigned short* __restrict__ csr,
                                                  const int* __restrict__ row_off,
                                                  const float* __restrict__ dinv,
                                                  const float* __restrict__ bias,
                                                  void* __restrict__ outp, int gbase, int Cg) {
  int bid = blockIdx.x;
  int gw = bid % Cg, xb = bid / Cg;
  const unsigned short* hg = h1 + (size_t)gw * NN * F;
  const unsigned short* cs = csr + (size_t)gw * EE;
  const int*   ro = row_off + gw * (NN + 1);
  const float* dv = dinv + (size_t)gw * NN;

  int grp = threadIdx.x >> 4, lane = threadIdx.x & 15;
  int node = xb * 16 + grp;                   // 3125*16 == 50000 exact
  int e0 = ro[node], e1 = ro[node + 1];
  float di = dv[node];
  f32x4 a0 = {0.f, 0.f, 0.f, 0.f}, b0 = a0, a1 = a0, b1 = a0;
  addrow(a0, b0, *(const u16x8*)(hg + (size_t)node * F + lane * 8));   // self (scaled)
  int e = e0;
  for (; e + 3 < e1; e += 4) {
    int s0 = cs[e], s1 = cs[e + 1], s2 = cs[e + 2], s3 = cs[e + 3];
    u16x8 v0 = *(const u16x8*)(hg + (size_t)s0 * F + lane * 8);
    u16x8 v1 = *(const u16x8*)(hg + (size_t)s1 * F + lane * 8);
    u16x8 v2 = *(const u16x8*)(hg + (size_t)s2 * F + lane * 8);
    u16x8 v3 = *(const u16x8*)(hg + (size_t)s3 * F + lane * 8);
    addrow(a0, b0, v0);
    addrow(a1, b1, v1);
    addrow(a0, b0, v2);
    addrow(a1, b1, v3);
  }
  for (; e < e1; ++e) {
    int s = cs[e];
    addrow(a0, b0, *(const u16x8*)(hg + (size_t)s * F + lane * 8));
  }
  f32x4 ra = a0 + a1, rb = b0 + b1;
  float4_t bb0 = *(const float4_t*)(bias + lane * 8);
  float4_t bb1 = *(const float4_t*)(bias + lane * 8 + 4);
  #pragma unroll
  for (int j = 0; j < 4; ++j) {
    ra[j] = fmaxf(fmaf(ra[j], di, bb0[j]), 0.f);
    rb[j] = fmaxf(fmaf(rb[j], di, bb1[j]), 0.f);
  }
  if (FIN) {
    float* og = (float*)outp + (size_t)(gbase + gw) * NN * F + (size_t)node * F + lane * 8;
    __builtin_nontemporal_store(ra, (f32x4*)og);       // d_out never re-read
    __builtin_nontemporal_store(rb, (f32x4*)(og + 4));
  } else {
    u16x8 o;
    #pragma unroll
    for (int j = 0; j < 4; ++j) { o[j] = f2bf(ra[j]); o[j + 4] = f2bf(rb[j]); }
    unsigned short* og = (unsigned short*)outp + (size_t)gw * NN * F + (size_t)node * F + lane * 8;
    *(u16x8*)og = o;                                   // regular: gemm re-reads warm
  }
}

// ---------------- host launch ----------------

extern "C" void kernel_launch(void* const* d_in, const int* in_sizes, int n_in,
                              void* d_out, int out_size, void* d_ws, size_t ws_size,
                              hipStream_t stream) {
  const float* x     = (const float*)d_in[0];
  const int*   edges = (const int*)d_in[1];
  const float* Ws[3] = {(const float*)d_in[2], (const float*)d_in[4], (const float*)d_in[6]};
  const float* bs[3] = {(const float*)d_in[3], (const float*)d_in[5], (const float*)d_in[7]};
  float* out = (float*)d_out;

  size_t sz_h1  = (size_t)NN * F * 2;           // 12.8 MB bf16 per graph (x2: h1 + actb)
  size_t sz_wt  = (size_t)3 * 2 * F * F * 2;
  size_t sz_csr = (size_t)EE * 2;               // u16 CSR
  size_t sz_bk  = (size_t)NBK * 4;
  size_t sz_dv  = (size_t)NN * 4;
  size_t sz_ro  = (size_t)(NN + 1) * 4;
  // binA tmp (3.6MB) aliases actb: build completes before agg writes actb
  size_t per_g  = 2 * sz_h1 + sz_csr + 2 * sz_bk + sz_dv + sz_ro;  // ~27.8 MB

  int CB = (int)((ws_size > sz_wt ? ws_size - sz_wt : 0) / per_g);
  if (CB < 1) CB = 1;
  if (CB > G) CB = G;

  char* p = (char*)d_ws;
  unsigned short* h1      = (unsigned short*)p;  p += sz_h1 * CB;
  unsigned short* actb    = (unsigned short*)p;  p += sz_h1 * CB;   // also binA tmp
  __bf16*         wt      = (__bf16*)p;          p += sz_wt;
  unsigned short* csr     = (unsigned short*)p;  p += sz_csr * CB;
  int*            bcur    = (int*)p;             p += sz_bk * CB;
  int*            bbase   = (int*)p;             p += sz_bk * CB;
  float*          dinv    = (float*)p;           p += sz_dv * CB;
  int*            row_off = (int*)p;

  wtprep_kernel<<<3, 256, 0, stream>>>(Ws[0], Ws[1], Ws[2], wt);

  int nblk_g = (NN + 63) / 64;   // 782 gemm blocks per graph
  int nblk_a = NN / 16;          // 3125

  for (int gb = 0; gb < G; gb += CB) {
    int Cg = G - gb < CB ? G - gb : CB;
    hipMemsetAsync(bcur, 0, sz_bk * Cg, stream);
    binA_kernel <<<NBA * Cg, 256, 0, stream>>>(edges, bcur, (unsigned int*)actb, gb, Cg);
    bscan_kernel<<<Cg, 256, 0, stream>>>(bcur, bbase);
    binB_kernel <<<NBK * Cg, 256, 0, stream>>>((const unsigned int*)actb, bcur, bbase,
                                               csr, row_off, dinv, Cg);

    // layer 0
    gemm0_kernel<<<nblk_g * Cg, 256, 0, stream>>>(x, wt, dinv, h1, gb, Cg);
    agg_kernel<0><<<nblk_a * Cg, 256, 0, stream>>>(h1, csr, row_off, dinv, bs[0], actb, gb, Cg);
    // layer 1
    gemm1_kernel<<<nblk_g * Cg, 256, 0, stream>>>(actb, wt + 2 * F * F, dinv, h1, Cg);
    agg_kernel<0><<<nblk_a * Cg, 256, 0, stream>>>(h1, csr, row_off, dinv, bs[1], actb, gb, Cg);
    // layer 2
    gemm1_kernel<<<nblk_g * Cg, 256, 0, stream>>>(actb, wt + 4 * F * F, dinv, h1, Cg);
    agg_kernel<1><<<nblk_a * Cg, 256, 0, stream>>>(h1, csr, row_off, dinv, bs[2], out, gb, Cg);
  }
}